// Round 2
// baseline (6584.992 us; speedup 1.0000x reference)
//
#include <hip/hip_runtime.h>

constexpr int C = 1024, H = 256, V = 10000, K = 32, B = 8, T = 256, K1K = 65;
constexpr int GRID = 256, JPB = 8, BSUB = 4;
constexpr float LV = 9.210340371976184f;  // ln(10000)

#define DEV static __device__ __forceinline__

DEV unsigned encf(float f) {
  unsigned u = __float_as_uint(f);
  return (u & 0x80000000u) ? ~u : (u | 0x80000000u);
}
DEV float decf(unsigned e) {
  unsigned u = (e & 0x80000000u) ? (e & 0x7fffffffu) : ~e;
  return __uint_as_float(u);
}

// device-wide barrier: monotone target, counter zeroed by k_init each launch
DEV void gbar(unsigned* cnt, unsigned target) {
  __syncthreads();
  if (threadIdx.x == 0) {
    __threadfence();  // release: flush L2 (cross-XCD visibility of our stores)
    __hip_atomic_fetch_add(cnt, 1u, __ATOMIC_RELEASE, __HIP_MEMORY_SCOPE_AGENT);
    while (__hip_atomic_load(cnt, __ATOMIC_RELAXED, __HIP_MEMORY_SCOPE_AGENT) < target)
      __builtin_amdgcn_s_sleep(2);
    __threadfence();  // acquire: invalidate L1/L2 so fresh u/umax are read
  }
  __syncthreads();
}

// ---------- init: zero barrier counter, reset umax slots ----------
__global__ void k_init(unsigned* barcnt, unsigned* umax) {
  int i = threadIdx.x;
  if (i == 0) *barcnt = 0;
  if (i < 32 * B) umax[i] = 0x80000000u;  // encf(0)
}

// ---------- start vector: MLP + log_softmax over C ----------
__global__ void __launch_bounds__(256) k_start(
    const float* __restrict__ semb, const float* __restrict__ linW, const float* __restrict__ linb,
    const float* __restrict__ rW1, const float* __restrict__ rb1,
    const float* __restrict__ rW2, const float* __restrict__ rb2,
    const float* __restrict__ nse, float* __restrict__ startv) {
  __shared__ float sa[H], fx[H], hh[H], sl[C], red[256];
  int tid = threadIdx.x;
  sa[tid] = semb[tid];
  __syncthreads();
  float acc = linb[tid];
  for (int h = 0; h < H; ++h) acc += sa[h] * linW[tid * H + h];
  fx[tid] = acc;
  __syncthreads();
  for (int l = 0; l < 2; ++l) {
    float a1 = rb1[l * H + tid];
    const float* w1 = rW1 + (size_t)l * H * H + (size_t)tid * H;
    for (int h = 0; h < H; ++h) a1 += fx[h] * w1[h];
    hh[tid] = fmaxf(a1, 0.f);
    __syncthreads();
    float a2 = rb2[l * H + tid];
    const float* w2 = rW2 + (size_t)l * H * H + (size_t)tid * H;
    for (int h = 0; h < H; ++h) a2 += hh[h] * w2[h];
    __syncthreads();
    fx[tid] += fmaxf(a2, 0.f);
    __syncthreads();
  }
  for (int q = 0; q < 4; ++q) {
    int c = q * 256 + tid;
    const float* nr = nse + (size_t)c * H;
    float s = 0.f;
    for (int h = 0; h < H; ++h) s += fx[h] * nr[h];
    sl[c] = s;
  }
  __syncthreads();
  float m = -__builtin_inff();
  for (int q = 0; q < 4; ++q) m = fmaxf(m, sl[q * 256 + tid]);
  red[tid] = m; __syncthreads();
  for (int off = 128; off > 0; off >>= 1) { if (tid < off) red[tid] = fmaxf(red[tid], red[tid + off]); __syncthreads(); }
  m = red[0]; __syncthreads();
  float s = 0.f;
  for (int q = 0; q < 4; ++q) s += __expf(sl[q * 256 + tid] - m);
  red[tid] = s; __syncthreads();
  for (int off = 128; off > 0; off >>= 1) { if (tid < off) red[tid] += red[tid + off]; __syncthreads(); }
  float lse = m + __logf(red[0]);
  for (int q = 0; q < 4; ++q) { int c = q * 256 + tid; startv[c] = sl[c] - lse; }
}

// ---------- terminal MLP ----------
__global__ void __launch_bounds__(256) k_term_mlp(
    const float* __restrict__ pre,
    const float* __restrict__ rW1, const float* __restrict__ rb1,
    const float* __restrict__ rW2, const float* __restrict__ rb2,
    float* __restrict__ ft) {
  __shared__ float x[4][H], hh[4][H];
  int tid = threadIdx.x;
  int r0 = blockIdx.x * 4;
  for (int r = 0; r < 4; ++r) x[r][tid] = pre[(size_t)(r0 + r) * H + tid];
  __syncthreads();
  for (int l = 0; l < 2; ++l) {
    float bb = rb1[l * H + tid];
    float a0 = bb, a1 = bb, a2 = bb, a3 = bb;
    const float* w1 = rW1 + (size_t)l * H * H + (size_t)tid * H;
    for (int h = 0; h < H; ++h) {
      float w = w1[h];
      a0 += x[0][h] * w; a1 += x[1][h] * w; a2 += x[2][h] * w; a3 += x[3][h] * w;
    }
    hh[0][tid] = fmaxf(a0, 0.f); hh[1][tid] = fmaxf(a1, 0.f);
    hh[2][tid] = fmaxf(a2, 0.f); hh[3][tid] = fmaxf(a3, 0.f);
    __syncthreads();
    bb = rb2[l * H + tid];
    float b0 = bb, b1 = bb, b2 = bb, b3 = bb;
    const float* w2 = rW2 + (size_t)l * H * H + (size_t)tid * H;
    for (int h = 0; h < H; ++h) {
      float w = w2[h];
      b0 += hh[0][h] * w; b1 += hh[1][h] * w; b2 += hh[2][h] * w; b3 += hh[3][h] * w;
    }
    __syncthreads();
    x[0][tid] += fmaxf(b0, 0.f); x[1][tid] += fmaxf(b1, 0.f);
    x[2][tid] += fmaxf(b2, 0.f); x[3][tid] += fmaxf(b3, 0.f);
    __syncthreads();
  }
  for (int r = 0; r < 4; ++r) ft[(size_t)(r0 + r) * H + tid] = x[r][tid];
}

// ---------- transition: PT[j][i] = P[i][j] = softmax_j(logits+band) ----------
__global__ void __launch_bounds__(256) k_trans(
    const float* __restrict__ se, const float* __restrict__ nse,
    const float* __restrict__ band, float* __restrict__ PT) {
  __shared__ float sl[C];
  __shared__ float rr[256];
  int i = blockIdx.x;
  int tid = threadIdx.x, lane = tid & 63, w = tid >> 6;
  float4 sv = ((const float4*)(se + (size_t)i * H))[lane];
  for (int q = 0; q < 256; ++q) {
    int j = w * 256 + q;
    float4 nv = ((const float4*)(nse + (size_t)j * H))[lane];
    float p = sv.x * nv.x + sv.y * nv.y + sv.z * nv.z + sv.w * nv.w;
    #pragma unroll
    for (int off = 32; off > 0; off >>= 1) p += __shfl_xor(p, off);
    if (lane == 0) sl[j] = p;
  }
  __syncthreads();
  if (tid < K1K) {
    int col = i + tid - K;
    if (col >= 0 && col < C) sl[col] += band[(size_t)i * K1K + tid];
  }
  __syncthreads();
  float m = -__builtin_inff();
  for (int q = 0; q < 4; ++q) m = fmaxf(m, sl[q * 256 + tid]);
  rr[tid] = m; __syncthreads();
  for (int off = 128; off > 0; off >>= 1) { if (tid < off) rr[tid] = fmaxf(rr[tid], rr[tid + off]); __syncthreads(); }
  m = rr[0]; __syncthreads();
  float e[4]; float s = 0.f;
  for (int q = 0; q < 4; ++q) { e[q] = __expf(sl[q * 256 + tid] - m); s += e[q]; }
  rr[tid] = s; __syncthreads();
  for (int off = 128; off > 0; off >>= 1) { if (tid < off) rr[tid] += rr[tid + off]; __syncthreads(); }
  float inv = 1.f / rr[0];
  for (int q = 0; q < 4; ++q) {
    int j = q * 256 + tid;
    PT[(size_t)j * C + i] = e[q] * inv;
  }
}

// ---------- emission denominators ----------
__global__ void __launch_bounds__(256) k_denom_part(
    const float* __restrict__ ft, const float* __restrict__ term, float* __restrict__ dpart) {
  constexpr int TJ = 16, VC = V / 8;
  __shared__ float shm[TJ * 4], shs[TJ * 4];
  int tid = threadIdx.x, lane = tid & 63, w = tid >> 6;
  int jg = blockIdx.x >> 3, vc = blockIdx.x & 7;
  const float4* fb = (const float4*)(ft + (size_t)jg * TJ * H);
  float rm[TJ], rs[TJ];
  #pragma unroll
  for (int r = 0; r < TJ; ++r) { rm[r] = -__builtin_inff(); rs[r] = 0.f; }
  int v0 = vc * VC;
  for (int v = v0 + tid; v < v0 + VC; v += 256) {
    const float4* tr = (const float4*)(term + (size_t)v * H);
    float acc[TJ];
    #pragma unroll
    for (int r = 0; r < TJ; ++r) acc[r] = 0.f;
    for (int h4 = 0; h4 < H / 4; ++h4) {
      float4 tv = tr[h4];
      #pragma unroll
      for (int r = 0; r < TJ; ++r) {
        float4 f = fb[r * (H / 4) + h4];
        acc[r] += tv.x * f.x + tv.y * f.y + tv.z * f.z + tv.w * f.w;
      }
    }
    #pragma unroll
    for (int r = 0; r < TJ; ++r) {
      float m2 = fmaxf(rm[r], acc[r]);
      rs[r] = rs[r] * __expf(rm[r] - m2) + __expf(acc[r] - m2);
      rm[r] = m2;
    }
  }
  #pragma unroll
  for (int r = 0; r < TJ; ++r) {
    float m = rm[r], s = rs[r];
    #pragma unroll
    for (int off = 32; off > 0; off >>= 1) {
      float mo = __shfl_xor(m, off), so = __shfl_xor(s, off);
      float m2 = fmaxf(m, mo);
      s = s * __expf(m - m2) + so * __expf(mo - m2);
      m = m2;
    }
    if (lane == 0) { shm[r * 4 + w] = m; shs[r * 4 + w] = s; }
  }
  __syncthreads();
  if (tid < TJ) {
    float m = -__builtin_inff(), s = 0.f;
    for (int w2 = 0; w2 < 4; ++w2) {
      float mo = shm[tid * 4 + w2], so = shs[tid * 4 + w2];
      float m2 = fmaxf(m, mo);
      s = s * __expf(m - m2) + so * __expf(mo - m2);
      m = m2;
    }
    int j = jg * TJ + tid;
    dpart[(j * 8 + vc) * 2 + 0] = m;
    dpart[(j * 8 + vc) * 2 + 1] = s;
  }
}

__global__ void k_denom_comb(const float* __restrict__ dpart, float* __restrict__ denom) {
  int j = blockIdx.x * 256 + threadIdx.x;
  float m = -__builtin_inff(), s = 0.f;
  for (int vc = 0; vc < 8; ++vc) {
    float mo = dpart[(j * 8 + vc) * 2], so = dpart[(j * 8 + vc) * 2 + 1];
    float m2 = fmaxf(m, mo);
    s = s * __expf(m - m2) + so * __expf(mo - m2);
    m = m2;
  }
  denom[j] = m + __logf(s);
}

// ---------- eem[(t*B+b)*C + j] = exp(ft[j]·term[tok] - denom[j] + LV) ----------
__global__ void __launch_bounds__(256) k_eemit(
    const int* __restrict__ text, const float* __restrict__ ft,
    const float* __restrict__ denom, const float* __restrict__ term,
    float* __restrict__ eem) {
  int tid = threadIdx.x;
  int n0 = blockIdx.x * 8;
  const float4* trow[8];
  #pragma unroll
  for (int r = 0; r < 8; ++r) {
    int n = n0 + r;
    int tok = text[(n & 7) * T + (n >> 3)];  // text[b*T + t], n = t*B+b
    trow[r] = (const float4*)(term + (size_t)tok * H);
  }
  for (int q = 0; q < 4; ++q) {
    int j = q * 256 + tid;
    const float4* fr = (const float4*)(ft + (size_t)j * H);
    float acc[8];
    #pragma unroll
    for (int r = 0; r < 8; ++r) acc[r] = 0.f;
    for (int h4 = 0; h4 < H / 4; ++h4) {
      float4 f = fr[h4];
      #pragma unroll
      for (int r = 0; r < 8; ++r) {
        float4 tv = trow[r][h4];
        acc[r] += f.x * tv.x + f.y * tv.y + f.z * tv.z + f.w * tv.w;
      }
    }
    float dj = denom[j];
    #pragma unroll
    for (int r = 0; r < 8; ++r) eem[(size_t)(n0 + r) * C + j] = __expf(acc[r] - dj + LV);
  }
}

// ---------- persistent linear-space scan ----------
// block: bh = blockIdx&1 -> batches bh*4..bh*4+3; jg = blockIdx>>1 -> j's jg*8..jg*8+7
// wave w owns j = jg*8 + w*2 + {0,1}. u_t[b,j] = (sum_i u_{t-1}[b,i] PT[j,i]) * eem_t[b,j] * invm
__global__ void __launch_bounds__(256, 1) k_scan(
    const float* __restrict__ PT, const float* __restrict__ eem,
    const float* __restrict__ startv, float* __restrict__ ua, float* __restrict__ ub,
    unsigned* __restrict__ umax, unsigned* __restrict__ barcnt, float* __restrict__ out) {
  __shared__ float sred[4][8];
  __shared__ float fred[256];
  const int tid = threadIdx.x, lane = tid & 63, w = tid >> 6;
  const int bh = blockIdx.x & 1, jg = (int)blockIdx.x >> 1;
  const int b0 = bh * BSUB;
  const int jbase = jg * JPB;
  const int jA = jbase + w * 2, jB = jA + 1;

  // u_0 = exp(startv + emit_0 + LV); cumulative scale S_0 = -LV (folded into -T*LV at end)
  if (tid < JPB * BSUB) {
    int jj = tid & 7, bb = tid >> 3;
    int j = jbase + jj, b = b0 + bb;
    ua[b * C + j] = __expf(startv[j]) * eem[(size_t)b * C + j];
  }
  unsigned target = GRID;
  gbar(barcnt, target); target += GRID;

  float Sacc0 = 0.f, Sacc1 = 0.f, Sacc2 = 0.f, Sacc3 = 0.f;
  const float* ucur = ua;
  float* unxt = ub;

  for (int t = 1; t < T; ++t) {
    float im0 = 1.f, im1 = 1.f, im2 = 1.f, im3 = 1.f;
    if (((t - 1) & 7) == 0 && t > 1) {
      int slot = (t - 1) >> 3;
      float m0 = decf(umax[slot * B + b0 + 0]);
      float m1 = decf(umax[slot * B + b0 + 1]);
      float m2 = decf(umax[slot * B + b0 + 2]);
      float m3 = decf(umax[slot * B + b0 + 3]);
      im0 = 1.f / m0; im1 = 1.f / m1; im2 = 1.f / m2; im3 = 1.f / m3;
      Sacc0 += __logf(m0); Sacc1 += __logf(m1); Sacc2 += __logf(m2); Sacc3 += __logf(m3);
    }
    const float* p0 = PT + (size_t)jA * C;
    const float* p1 = PT + (size_t)jB * C;
    const float* u0p = ucur + (b0 + 0) * C;
    const float* u1p = ucur + (b0 + 1) * C;
    const float* u2p = ucur + (b0 + 2) * C;
    const float* u3p = ucur + (b0 + 3) * C;
    float a00 = 0, a01 = 0, a02 = 0, a03 = 0, a10 = 0, a11 = 0, a12 = 0, a13 = 0;
    #pragma unroll
    for (int k = 0; k < 16; ++k) {
      int i = k * 64 + lane;
      float q0 = p0[i], q1 = p1[i];
      float x0 = u0p[i], x1 = u1p[i], x2 = u2p[i], x3 = u3p[i];
      a00 += q0 * x0; a01 += q0 * x1; a02 += q0 * x2; a03 += q0 * x3;
      a10 += q1 * x0; a11 += q1 * x1; a12 += q1 * x2; a13 += q1 * x3;
    }
    #pragma unroll
    for (int off = 32; off > 0; off >>= 1) {
      a00 += __shfl_xor(a00, off); a01 += __shfl_xor(a01, off);
      a02 += __shfl_xor(a02, off); a03 += __shfl_xor(a03, off);
      a10 += __shfl_xor(a10, off); a11 += __shfl_xor(a11, off);
      a12 += __shfl_xor(a12, off); a13 += __shfl_xor(a13, off);
    }
    if (lane < 8) {
      int jj = lane >> 2, bb = lane & 3;
      float acc = jj ? ((bb == 0) ? a10 : (bb == 1) ? a11 : (bb == 2) ? a12 : a13)
                     : ((bb == 0) ? a00 : (bb == 1) ? a01 : (bb == 2) ? a02 : a03);
      float im = (bb == 0) ? im0 : (bb == 1) ? im1 : (bb == 2) ? im2 : im3;
      int j = jA + jj;
      int b = b0 + bb;
      float val = acc * im * eem[((size_t)t * B + b) * C + j];
      unxt[b * C + j] = val;
      sred[w][lane] = val;
    }
    if ((t & 7) == 0) {
      __syncthreads();
      if (tid < BSUB) {
        float m = sred[0][tid];
        #pragma unroll
        for (int ww = 0; ww < 4; ++ww) {
          m = fmaxf(m, sred[ww][tid]);
          m = fmaxf(m, sred[ww][4 + tid]);
        }
        atomicMax(&umax[(t >> 3) * B + b0 + tid], encf(m));
      }
    }
    gbar(barcnt, target); target += GRID;
    const float* tp = ucur; ucur = unxt; unxt = (float*)tp;
  }

  // final: blocks 0,1 compute out[b] = -T*LV + Sacc[b] + log(sum_j u_T[b,j])
  if (blockIdx.x < 2) {
    for (int bb = 0; bb < BSUB; ++bb) {
      const float* uf = ucur + (size_t)(b0 + bb) * C;
      float s = uf[tid] + uf[tid + 256] + uf[tid + 512] + uf[tid + 768];
      fred[tid] = s;
      __syncthreads();
      for (int off = 128; off > 0; off >>= 1) {
        if (tid < off) fred[tid] += fred[tid + off];
        __syncthreads();
      }
      if (tid == 0) {
        float Sb = (bb == 0) ? Sacc0 : (bb == 1) ? Sacc1 : (bb == 2) ? Sacc2 : Sacc3;
        out[b0 + bb] = -(float)T * LV + Sb + __logf(fred[0]);
      }
      __syncthreads();
    }
  }
}

extern "C" void kernel_launch(void* const* d_in, const int* in_sizes, int n_in,
                              void* d_out, int out_size, void* d_ws, size_t ws_size,
                              hipStream_t stream) {
  const int*   text  = (const int*)  d_in[0];
  const float* semb  = (const float*)d_in[1];
  const float* slinW = (const float*)d_in[2];
  const float* slinb = (const float*)d_in[3];
  const float* srW1  = (const float*)d_in[4];
  const float* srb1  = (const float*)d_in[5];
  const float* srW2  = (const float*)d_in[6];
  const float* srb2  = (const float*)d_in[7];
  const float* stemb = (const float*)d_in[8];
  const float* nse   = (const float*)d_in[9];
  const float* pre   = (const float*)d_in[10];
  const float* trW1  = (const float*)d_in[11];
  const float* trb1  = (const float*)d_in[12];
  const float* trW2  = (const float*)d_in[13];
  const float* trb2  = (const float*)d_in[14];
  const float* term  = (const float*)d_in[15];
  const float* band  = (const float*)d_in[16];

  float* ws     = (float*)d_ws;
  float* PT     = ws;                          // C*C
  float* eem    = PT + (size_t)C * C;          // T*B*C
  float* ua     = eem + (size_t)T * B * C;     // B*C
  float* ubuf   = ua + B * C;                  // B*C
  float* ftb    = ubuf + B * C;                // C*H
  float* startv = ftb + (size_t)C * H;         // C
  float* denom  = startv + C;                  // C
  float* dpart  = denom + C;                   // C*16
  unsigned* umax   = (unsigned*)(dpart + C * 16);  // 32*B
  unsigned* barcnt = umax + 32 * B;                // 1

  k_init<<<1, 256, 0, stream>>>(barcnt, umax);
  k_start<<<1, 256, 0, stream>>>(semb, slinW, slinb, srW1, srb1, srW2, srb2, nse, startv);
  k_term_mlp<<<C / 4, 256, 0, stream>>>(pre, trW1, trb1, trW2, trb2, ftb);
  k_trans<<<C, 256, 0, stream>>>(stemb, nse, band, PT);
  k_denom_part<<<(C / 16) * 8, 256, 0, stream>>>(ftb, term, dpart);
  k_denom_comb<<<C / 256, 256, 0, stream>>>(dpart, denom);
  k_eemit<<<(T * B) / 8, 256, 0, stream>>>(text, ftb, denom, term, eem);
  k_scan<<<GRID, 256, 0, stream>>>(PT, eem, startv, ua, ubuf, umax, barcnt, (float*)d_out);
}

// Round 3
// 2671.610 us; speedup vs baseline: 2.4648x; 2.4648x over previous
//
#include <hip/hip_runtime.h>

constexpr int C = 1024, H = 256, V = 10000, K = 32, B = 8, T = 256, K1K = 65;
constexpr int GS = 128;  // scan blocks: 64 j-groups x 2 batch-halves
constexpr float LV = 9.210340371976184f;  // ln(10000)

#define DEV static __device__ __forceinline__

typedef float f4 __attribute__((ext_vector_type(4)));

DEV void gstore(float* p, float v) {
  __hip_atomic_store((unsigned*)p, __float_as_uint(v), __ATOMIC_RELAXED, __HIP_MEMORY_SCOPE_AGENT);
}
DEV float gload(const float* p) {
  return __uint_as_float(__hip_atomic_load((unsigned*)p, __ATOMIC_RELAXED, __HIP_MEMORY_SCOPE_AGENT));
}

// RMW-free device barrier: per-block epoch flags (64B apart), parallel poll.
DEV void gsync(unsigned* flags, int bid, unsigned ep) {
  __syncthreads();  // drains vmcnt(0): all sc0/sc1 stores globally visible
  if (threadIdx.x == 0)
    __hip_atomic_store(&flags[bid * 16], ep, __ATOMIC_RELEASE, __HIP_MEMORY_SCOPE_AGENT);
  if (threadIdx.x < GS) {
    while (__hip_atomic_load(&flags[threadIdx.x * 16], __ATOMIC_ACQUIRE,
                             __HIP_MEMORY_SCOPE_AGENT) < ep) {}
  }
  __syncthreads();
}

// ---------- init: zero barrier flags ----------
__global__ void k_init(unsigned* flags) {
  int tid = threadIdx.x;
  for (int k = 0; k < (GS * 16) / 256; ++k) flags[k * 256 + tid] = 0u;
}

// ---------- start vector: MLP + log_softmax over C ----------
__global__ void __launch_bounds__(256) k_start(
    const float* __restrict__ semb, const float* __restrict__ linW, const float* __restrict__ linb,
    const float* __restrict__ rW1, const float* __restrict__ rb1,
    const float* __restrict__ rW2, const float* __restrict__ rb2,
    const float* __restrict__ nse, float* __restrict__ startv) {
  __shared__ float sa[H], fx[H], hh[H], sl[C], red[256];
  int tid = threadIdx.x;
  sa[tid] = semb[tid];
  __syncthreads();
  float acc = linb[tid];
  for (int h = 0; h < H; ++h) acc += sa[h] * linW[tid * H + h];
  fx[tid] = acc;
  __syncthreads();
  for (int l = 0; l < 2; ++l) {
    float a1 = rb1[l * H + tid];
    const float* w1 = rW1 + (size_t)l * H * H + (size_t)tid * H;
    for (int h = 0; h < H; ++h) a1 += fx[h] * w1[h];
    hh[tid] = fmaxf(a1, 0.f);
    __syncthreads();
    float a2 = rb2[l * H + tid];
    const float* w2 = rW2 + (size_t)l * H * H + (size_t)tid * H;
    for (int h = 0; h < H; ++h) a2 += hh[h] * w2[h];
    __syncthreads();
    fx[tid] += fmaxf(a2, 0.f);
    __syncthreads();
  }
  for (int q = 0; q < 4; ++q) {
    int c = q * 256 + tid;
    const float* nr = nse + (size_t)c * H;
    float s = 0.f;
    for (int h = 0; h < H; ++h) s += fx[h] * nr[h];
    sl[c] = s;
  }
  __syncthreads();
  float m = -__builtin_inff();
  for (int q = 0; q < 4; ++q) m = fmaxf(m, sl[q * 256 + tid]);
  red[tid] = m; __syncthreads();
  for (int off = 128; off > 0; off >>= 1) { if (tid < off) red[tid] = fmaxf(red[tid], red[tid + off]); __syncthreads(); }
  m = red[0]; __syncthreads();
  float s = 0.f;
  for (int q = 0; q < 4; ++q) s += __expf(sl[q * 256 + tid] - m);
  red[tid] = s; __syncthreads();
  for (int off = 128; off > 0; off >>= 1) { if (tid < off) red[tid] += red[tid + off]; __syncthreads(); }
  float lse = m + __logf(red[0]);
  for (int q = 0; q < 4; ++q) { int c = q * 256 + tid; startv[c] = sl[c] - lse; }
}

// ---------- terminal MLP ----------
__global__ void __launch_bounds__(256) k_term_mlp(
    const float* __restrict__ pre,
    const float* __restrict__ rW1, const float* __restrict__ rb1,
    const float* __restrict__ rW2, const float* __restrict__ rb2,
    float* __restrict__ ft) {
  __shared__ float x[4][H], hh[4][H];
  int tid = threadIdx.x;
  int r0 = blockIdx.x * 4;
  for (int r = 0; r < 4; ++r) x[r][tid] = pre[(size_t)(r0 + r) * H + tid];
  __syncthreads();
  for (int l = 0; l < 2; ++l) {
    float bb = rb1[l * H + tid];
    float a0 = bb, a1 = bb, a2 = bb, a3 = bb;
    const float* w1 = rW1 + (size_t)l * H * H + (size_t)tid * H;
    for (int h = 0; h < H; ++h) {
      float w = w1[h];
      a0 += x[0][h] * w; a1 += x[1][h] * w; a2 += x[2][h] * w; a3 += x[3][h] * w;
    }
    hh[0][tid] = fmaxf(a0, 0.f); hh[1][tid] = fmaxf(a1, 0.f);
    hh[2][tid] = fmaxf(a2, 0.f); hh[3][tid] = fmaxf(a3, 0.f);
    __syncthreads();
    bb = rb2[l * H + tid];
    float b0 = bb, b1 = bb, b2 = bb, b3 = bb;
    const float* w2 = rW2 + (size_t)l * H * H + (size_t)tid * H;
    for (int h = 0; h < H; ++h) {
      float w = w2[h];
      b0 += hh[0][h] * w; b1 += hh[1][h] * w; b2 += hh[2][h] * w; b3 += hh[3][h] * w;
    }
    __syncthreads();
    x[0][tid] += fmaxf(b0, 0.f); x[1][tid] += fmaxf(b1, 0.f);
    x[2][tid] += fmaxf(b2, 0.f); x[3][tid] += fmaxf(b3, 0.f);
    __syncthreads();
  }
  for (int r = 0; r < 4; ++r) ft[(size_t)(r0 + r) * H + tid] = x[r][tid];
}

// ---------- transition: P[i][j] = softmax_j(se_i . nse_j + band), row-major store ----------
__global__ void __launch_bounds__(256) k_trans(
    const float* __restrict__ se, const float* __restrict__ nse,
    const float* __restrict__ band, float* __restrict__ Pm) {
  __shared__ float sv[H];
  __shared__ float sl[C];
  __shared__ float rr[256];
  int i = blockIdx.x, tid = threadIdx.x;
  sv[tid] = se[(size_t)i * H + tid];
  __syncthreads();
  #pragma unroll 1
  for (int jq = 0; jq < 4; ++jq) {
    int j = jq * 256 + tid;
    const float4* nr = (const float4*)(nse + (size_t)j * H);
    float acc = 0.f;
    #pragma unroll 8
    for (int h4 = 0; h4 < H / 4; ++h4) {
      float4 nv = nr[h4];
      float4 s4 = *(const float4*)&sv[h4 * 4];
      acc += s4.x * nv.x + s4.y * nv.y + s4.z * nv.z + s4.w * nv.w;
    }
    sl[j] = acc;
  }
  __syncthreads();
  if (tid < K1K) {
    int col = i + tid - K;
    if (col >= 0 && col < C) sl[col] += band[(size_t)i * K1K + tid];
  }
  __syncthreads();
  float m = -__builtin_inff();
  for (int q = 0; q < 4; ++q) m = fmaxf(m, sl[q * 256 + tid]);
  rr[tid] = m; __syncthreads();
  for (int off = 128; off > 0; off >>= 1) { if (tid < off) rr[tid] = fmaxf(rr[tid], rr[tid + off]); __syncthreads(); }
  m = rr[0]; __syncthreads();
  float e[4]; float s = 0.f;
  for (int q = 0; q < 4; ++q) { e[q] = __expf(sl[q * 256 + tid] - m); s += e[q]; }
  rr[tid] = s; __syncthreads();
  for (int off = 128; off > 0; off >>= 1) { if (tid < off) rr[tid] += rr[tid + off]; __syncthreads(); }
  float inv = 1.f / rr[0];
  for (int q = 0; q < 4; ++q) {
    int j = q * 256 + tid;
    Pm[(size_t)i * C + j] = e[q] * inv;  // coalesced row-major store
  }
}

// ---------- emission denominators ----------
__global__ void __launch_bounds__(256) k_denom_part(
    const float* __restrict__ ft, const float* __restrict__ term, float* __restrict__ dpart) {
  constexpr int TJ = 16, VC = V / 8;
  __shared__ float shm[TJ * 4], shs[TJ * 4];
  int tid = threadIdx.x, lane = tid & 63, w = tid >> 6;
  int jg = blockIdx.x >> 3, vc = blockIdx.x & 7;
  const float4* fb = (const float4*)(ft + (size_t)jg * TJ * H);
  float rm[TJ], rs[TJ];
  #pragma unroll
  for (int r = 0; r < TJ; ++r) { rm[r] = -__builtin_inff(); rs[r] = 0.f; }
  int v0 = vc * VC;
  for (int v = v0 + tid; v < v0 + VC; v += 256) {
    const float4* tr = (const float4*)(term + (size_t)v * H);
    float acc[TJ];
    #pragma unroll
    for (int r = 0; r < TJ; ++r) acc[r] = 0.f;
    for (int h4 = 0; h4 < H / 4; ++h4) {
      float4 tv = tr[h4];
      #pragma unroll
      for (int r = 0; r < TJ; ++r) {
        float4 f = fb[r * (H / 4) + h4];
        acc[r] += tv.x * f.x + tv.y * f.y + tv.z * f.z + tv.w * f.w;
      }
    }
    #pragma unroll
    for (int r = 0; r < TJ; ++r) {
      float m2 = fmaxf(rm[r], acc[r]);
      rs[r] = rs[r] * __expf(rm[r] - m2) + __expf(acc[r] - m2);
      rm[r] = m2;
    }
  }
  #pragma unroll
  for (int r = 0; r < TJ; ++r) {
    float m = rm[r], s = rs[r];
    #pragma unroll
    for (int off = 32; off > 0; off >>= 1) {
      float mo = __shfl_xor(m, off), so = __shfl_xor(s, off);
      float m2 = fmaxf(m, mo);
      s = s * __expf(m - m2) + so * __expf(mo - m2);
      m = m2;
    }
    if (lane == 0) { shm[r * 4 + w] = m; shs[r * 4 + w] = s; }
  }
  __syncthreads();
  if (tid < TJ) {
    float m = -__builtin_inff(), s = 0.f;
    for (int w2 = 0; w2 < 4; ++w2) {
      float mo = shm[tid * 4 + w2], so = shs[tid * 4 + w2];
      float m2 = fmaxf(m, mo);
      s = s * __expf(m - m2) + so * __expf(mo - m2);
      m = m2;
    }
    int j = jg * TJ + tid;
    dpart[(j * 8 + vc) * 2 + 0] = m;
    dpart[(j * 8 + vc) * 2 + 1] = s;
  }
}

__global__ void k_denom_comb(const float* __restrict__ dpart, float* __restrict__ denom) {
  int j = blockIdx.x * 256 + threadIdx.x;
  float m = -__builtin_inff(), s = 0.f;
  for (int vc = 0; vc < 8; ++vc) {
    float mo = dpart[(j * 8 + vc) * 2], so = dpart[(j * 8 + vc) * 2 + 1];
    float m2 = fmaxf(m, mo);
    s = s * __expf(m - m2) + so * __expf(mo - m2);
    m = m2;
  }
  denom[j] = m + __logf(s);
}

// ---------- eem[(t*B+b)*C + j] = exp(ft[j].term[tok] - denom[j] + LV) ----------
__global__ void __launch_bounds__(256) k_eemit(
    const int* __restrict__ text, const float* __restrict__ ft,
    const float* __restrict__ denom, const float* __restrict__ term,
    float* __restrict__ eem) {
  int tid = threadIdx.x;
  int n0 = blockIdx.x * 8;
  const float4* trow[8];
  #pragma unroll
  for (int r = 0; r < 8; ++r) {
    int n = n0 + r;
    int tok = text[(n & 7) * T + (n >> 3)];  // text[b*T + t], n = t*B+b
    trow[r] = (const float4*)(term + (size_t)tok * H);
  }
  for (int q = 0; q < 4; ++q) {
    int j = q * 256 + tid;
    const float4* fr = (const float4*)(ft + (size_t)j * H);
    float acc[8];
    #pragma unroll
    for (int r = 0; r < 8; ++r) acc[r] = 0.f;
    for (int h4 = 0; h4 < H / 4; ++h4) {
      float4 f = fr[h4];
      #pragma unroll
      for (int r = 0; r < 8; ++r) {
        float4 tv = trow[r][h4];
        acc[r] += f.x * tv.x + f.y * tv.y + f.z * tv.z + f.w * tv.w;
      }
    }
    float dj = denom[j];
    #pragma unroll
    for (int r = 0; r < 8; ++r) eem[(size_t)(n0 + r) * C + j] = __expf(acc[r] - dj + LV);
  }
}

// ---------- persistent linear-space scan ----------
// 128 blocks = 64 j-groups(16 j) x 2 batch-halves(4 b). Thread (jj=tid>>4, q=tid&15):
// owns P column slice [i in q*64..q*64+64) x (jbase+jj)] preloaded in 64 VGPRs.
__global__ void __launch_bounds__(256, 1) k_scan(
    const float* __restrict__ Pm, const float* __restrict__ eem,
    const float* __restrict__ startv, float* __restrict__ ua, float* __restrict__ ub,
    float* __restrict__ umax, unsigned* __restrict__ flags, float* __restrict__ out) {
  __shared__ __align__(16) float us[4 * 1088];   // swizzled: phys = bb*1088 + i + 4*(i>>6)
  __shared__ __align__(16) float part[16 * 64];  // [q][jj*4+bb]
  __shared__ float wval[64];
  __shared__ float fred[256];
  const int tid = threadIdx.x, bid = blockIdx.x;
  const int gb = bid & 1, gj = bid >> 1;
  const int b0 = gb * 4, jbase = gj * 16;
  const int jj = tid >> 4, q = tid & 15;
  const int myj = jbase + jj;
  const int i0 = q * 64;

  // preload P slice: pv[k4] = P[i0+4k4 .. +3][myj]  (static across all steps)
  f4 pv[16];
  #pragma unroll
  for (int k4 = 0; k4 < 16; ++k4) {
    f4 v;
    v.x = Pm[(size_t)(i0 + k4 * 4 + 0) * C + myj];
    v.y = Pm[(size_t)(i0 + k4 * 4 + 1) * C + myj];
    v.z = Pm[(size_t)(i0 + k4 * 4 + 2) * C + myj];
    v.w = Pm[(size_t)(i0 + k4 * 4 + 3) * C + myj];
    pv[k4] = v;
  }

  const int wjj = tid >> 2, wbb = tid & 3;  // writer role (tid<64)
  float Sacc = 0.f;

  // u_0 = exp(startv) * eem_0   (scale: T factors of e^{LV} folded out at the end)
  if (tid < 64) {
    int j = jbase + wjj, b = b0 + wbb;
    gstore(&ua[(size_t)b * C + j], __expf(startv[j]) * eem[(size_t)b * C + j]);
  }
  unsigned ep = 1;
  gsync(flags, bid, ep); ++ep;

  float* ucur = ua;
  float* unxt = ub;

  for (int t = 1; t < T; ++t) {
    // rescale factor (applied one step after sample-max write)
    float imt = 1.f, em = 0.f;
    if (tid < 64) {
      if ((t & 7) == 1 && t > 1) {
        float m = gload(&umax[((t - 1) >> 3) * 8 + b0 + wbb]);
        imt = 1.f / m;
        Sacc += __logf(m);
      }
      em = eem[((size_t)t * B + b0 + wbb) * C + jbase + wjj];
    }

    // stage u_prev (4 batches x 1024) into swizzled LDS via coherent 16B loads
    {
      const int f0 = tid * 16;
      const int sbb = f0 >> 10, si = f0 & 1023;
      const float* src = ucur + (size_t)(b0 + sbb) * C + si;
      f4 r0, r1, r2, r3;
      asm volatile(
          "global_load_dwordx4 %0, %4, off sc0 sc1\n\t"
          "global_load_dwordx4 %1, %4, off offset:16 sc0 sc1\n\t"
          "global_load_dwordx4 %2, %4, off offset:32 sc0 sc1\n\t"
          "global_load_dwordx4 %3, %4, off offset:48 sc0 sc1\n\t"
          "s_waitcnt vmcnt(0)"
          : "=&v"(r0), "=&v"(r1), "=&v"(r2), "=&v"(r3)
          : "v"(src)
          : "memory");
      int ph = sbb * 1088 + si + ((si >> 6) << 2);
      *(f4*)&us[ph] = r0;
      *(f4*)&us[ph + 4] = r1;
      *(f4*)&us[ph + 8] = r2;
      *(f4*)&us[ph + 12] = r3;
    }
    __syncthreads();

    // acc[bb] = sum_i u[bb][i] * P[i][myj] over i in [i0, i0+64)
    float a0 = 0.f, a1 = 0.f, a2 = 0.f, a3 = 0.f;
    const int ubo = q * 68;
    #pragma unroll
    for (int k4 = 0; k4 < 16; ++k4) {
      f4 p = pv[k4];
      f4 x0 = *(const f4*)&us[0 * 1088 + ubo + k4 * 4];
      f4 x1 = *(const f4*)&us[1 * 1088 + ubo + k4 * 4];
      f4 x2 = *(const f4*)&us[2 * 1088 + ubo + k4 * 4];
      f4 x3 = *(const f4*)&us[3 * 1088 + ubo + k4 * 4];
      a0 += p.x * x0.x + p.y * x0.y + p.z * x0.z + p.w * x0.w;
      a1 += p.x * x1.x + p.y * x1.y + p.z * x1.z + p.w * x1.w;
      a2 += p.x * x2.x + p.y * x2.y + p.z * x2.z + p.w * x2.w;
      a3 += p.x * x3.x + p.y * x3.y + p.z * x3.z + p.w * x3.w;
    }
    {
      f4 t4; t4.x = a0; t4.y = a1; t4.z = a2; t4.w = a3;
      *(f4*)&part[q * 64 + jj * 4] = t4;
    }
    __syncthreads();

    if (tid < 64) {
      float s = 0.f;
      #pragma unroll
      for (int q2 = 0; q2 < 16; ++q2) s += part[q2 * 64 + tid];
      float val = s * imt * em;
      gstore(&unxt[(size_t)(b0 + wbb) * C + jbase + wjj], val);
      if (gj == 0) wval[tid] = val;
    }
    if (gj == 0 && (t & 7) == 0) {  // sample-max over this block's 16 j's (exact scale not needed)
      __syncthreads();
      if (tid < 4) {
        float m = wval[tid];
        #pragma unroll
        for (int j2 = 1; j2 < 16; ++j2) m = fmaxf(m, wval[j2 * 4 + tid]);
        gstore(&umax[(t >> 3) * 8 + b0 + tid], m);
      }
    }
    gsync(flags, bid, ep); ++ep;
    float* tp = ucur; ucur = unxt; unxt = tp;
  }

  // final: blocks 0,1 -> out[b] = -T*LV + Sacc_b + log(sum_j u_T[b,j])
  if (gj == 0) {
    #pragma unroll 1
    for (int bb = 0; bb < 4; ++bb) {
      int b = b0 + bb;
      const float* uf = ucur + (size_t)b * C;
      float s = gload(&uf[tid]) + gload(&uf[tid + 256]) + gload(&uf[tid + 512]) + gload(&uf[tid + 768]);
      fred[tid] = s;
      __syncthreads();
      for (int off = 128; off > 0; off >>= 1) {
        if (tid < off) fred[tid] += fred[tid + off];
        __syncthreads();
      }
      if (tid == bb) out[b] = -(float)T * LV + Sacc + __logf(fred[0]);
      __syncthreads();
    }
  }
}

extern "C" void kernel_launch(void* const* d_in, const int* in_sizes, int n_in,
                              void* d_out, int out_size, void* d_ws, size_t ws_size,
                              hipStream_t stream) {
  const int*   text  = (const int*)  d_in[0];
  const float* semb  = (const float*)d_in[1];
  const float* slinW = (const float*)d_in[2];
  const float* slinb = (const float*)d_in[3];
  const float* srW1  = (const float*)d_in[4];
  const float* srb1  = (const float*)d_in[5];
  const float* srW2  = (const float*)d_in[6];
  const float* srb2  = (const float*)d_in[7];
  const float* stemb = (const float*)d_in[8];
  const float* nse   = (const float*)d_in[9];
  const float* pre   = (const float*)d_in[10];
  const float* trW1  = (const float*)d_in[11];
  const float* trb1  = (const float*)d_in[12];
  const float* trW2  = (const float*)d_in[13];
  const float* trb2  = (const float*)d_in[14];
  const float* term  = (const float*)d_in[15];
  const float* band  = (const float*)d_in[16];

  float* ws     = (float*)d_ws;
  float* Pm     = ws;                          // C*C (row-major P)
  float* eem    = Pm + (size_t)C * C;          // T*B*C
  float* ua     = eem + (size_t)T * B * C;     // B*C
  float* ubuf   = ua + B * C;                  // B*C
  float* ftb    = ubuf + B * C;                // C*H
  float* startv = ftb + (size_t)C * H;         // C
  float* denom  = startv + C;                  // C
  float* dpart  = denom + C;                   // C*16
  float* umax   = dpart + C * 16;              // 32*8
  unsigned* flags = (unsigned*)(umax + 32 * 8);  // GS*16

  k_init<<<1, 256, 0, stream>>>(flags);
  k_start<<<1, 256, 0, stream>>>(semb, slinW, slinb, srW1, srb1, srW2, srb2, nse, startv);
  k_term_mlp<<<C / 4, 256, 0, stream>>>(pre, trW1, trb1, trW2, trb2, ftb);
  k_trans<<<C, 256, 0, stream>>>(stemb, nse, band, Pm);
  k_denom_part<<<(C / 16) * 8, 256, 0, stream>>>(ftb, term, dpart);
  k_denom_comb<<<C / 256, 256, 0, stream>>>(dpart, denom);
  k_eemit<<<(T * B) / 8, 256, 0, stream>>>(text, ftb, denom, term, eem);
  k_scan<<<GS, 256, 0, stream>>>(Pm, eem, startv, ua, ubuf, umax, flags, (float*)d_out);
}

// Round 4
// 1498.796 us; speedup vs baseline: 4.3935x; 1.7825x over previous
//
#include <hip/hip_runtime.h>

constexpr int C = 1024, H = 256, V = 10000, K = 32, B = 8, T = 256, K1K = 65;
constexpr int GS = 128;  // scan blocks: 64 j-groups x 2 batch-halves
constexpr float LV = 9.210340371976184f;  // ln(10000)

#define DEV static __device__ __forceinline__

typedef float f4 __attribute__((ext_vector_type(4)));

DEV void gstore(float* p, float v) {
  __hip_atomic_store((unsigned*)p, __float_as_uint(v), __ATOMIC_RELAXED, __HIP_MEMORY_SCOPE_AGENT);
}
DEV float gload(const float* p) {
  return __uint_as_float(__hip_atomic_load((unsigned*)p, __ATOMIC_RELAXED, __HIP_MEMORY_SCOPE_AGENT));
}

// hierarchical device barrier (full version, used for the init step)
DEV void gsync(unsigned* flags, unsigned* gen, int bid, unsigned ep) {
  __syncthreads();
  if (threadIdx.x == 0) {
    asm volatile("s_waitcnt vmcnt(0)" ::: "memory");
    __hip_atomic_store(&flags[bid * 16], ep, __ATOMIC_RELAXED, __HIP_MEMORY_SCOPE_AGENT);
  }
  if (bid == 0) {
    if (threadIdx.x < GS)
      while (__hip_atomic_load(&flags[threadIdx.x * 16], __ATOMIC_RELAXED,
                               __HIP_MEMORY_SCOPE_AGENT) < ep) {}
    __syncthreads();
    if (threadIdx.x == 0)
      __hip_atomic_store(gen, ep, __ATOMIC_RELAXED, __HIP_MEMORY_SCOPE_AGENT);
  } else if (threadIdx.x == 0) {
    while (__hip_atomic_load(gen, __ATOMIC_RELAXED, __HIP_MEMORY_SCOPE_AGENT) < ep) {}
  }
  __syncthreads();
}

// ---------- init: zero barrier flags + gen ----------
__global__ void k_init(unsigned* flags) {
  int tid = threadIdx.x;
  for (int k = 0; k < 9; ++k) flags[k * 256 + tid] = 0u;  // GS*16 + gen area
}

// ---------- start vector: MLP + log_softmax over C ----------
__global__ void __launch_bounds__(256) k_start(
    const float* __restrict__ semb, const float* __restrict__ linW, const float* __restrict__ linb,
    const float* __restrict__ rW1, const float* __restrict__ rb1,
    const float* __restrict__ rW2, const float* __restrict__ rb2,
    const float* __restrict__ nse, float* __restrict__ startv) {
  __shared__ float sa[H], fx[H], hh[H], sl[C], red[256];
  int tid = threadIdx.x;
  sa[tid] = semb[tid];
  __syncthreads();
  float acc = linb[tid];
  for (int h = 0; h < H; ++h) acc += sa[h] * linW[tid * H + h];
  fx[tid] = acc;
  __syncthreads();
  for (int l = 0; l < 2; ++l) {
    float a1 = rb1[l * H + tid];
    const float* w1 = rW1 + (size_t)l * H * H + (size_t)tid * H;
    for (int h = 0; h < H; ++h) a1 += fx[h] * w1[h];
    hh[tid] = fmaxf(a1, 0.f);
    __syncthreads();
    float a2 = rb2[l * H + tid];
    const float* w2 = rW2 + (size_t)l * H * H + (size_t)tid * H;
    for (int h = 0; h < H; ++h) a2 += hh[h] * w2[h];
    __syncthreads();
    fx[tid] += fmaxf(a2, 0.f);
    __syncthreads();
  }
  for (int q = 0; q < 4; ++q) {
    int c = q * 256 + tid;
    const float* nr = nse + (size_t)c * H;
    float s = 0.f;
    for (int h = 0; h < H; ++h) s += fx[h] * nr[h];
    sl[c] = s;
  }
  __syncthreads();
  float m = -__builtin_inff();
  for (int q = 0; q < 4; ++q) m = fmaxf(m, sl[q * 256 + tid]);
  red[tid] = m; __syncthreads();
  for (int off = 128; off > 0; off >>= 1) { if (tid < off) red[tid] = fmaxf(red[tid], red[tid + off]); __syncthreads(); }
  m = red[0]; __syncthreads();
  float s = 0.f;
  for (int q = 0; q < 4; ++q) s += __expf(sl[q * 256 + tid] - m);
  red[tid] = s; __syncthreads();
  for (int off = 128; off > 0; off >>= 1) { if (tid < off) red[tid] += red[tid + off]; __syncthreads(); }
  float lse = m + __logf(red[0]);
  for (int q = 0; q < 4; ++q) { int c = q * 256 + tid; startv[c] = sl[c] - lse; }
}

// ---------- terminal MLP ----------
__global__ void __launch_bounds__(256) k_term_mlp(
    const float* __restrict__ pre,
    const float* __restrict__ rW1, const float* __restrict__ rb1,
    const float* __restrict__ rW2, const float* __restrict__ rb2,
    float* __restrict__ ft) {
  __shared__ float x[4][H], hh[4][H];
  int tid = threadIdx.x;
  int r0 = blockIdx.x * 4;
  for (int r = 0; r < 4; ++r) x[r][tid] = pre[(size_t)(r0 + r) * H + tid];
  __syncthreads();
  for (int l = 0; l < 2; ++l) {
    float bb = rb1[l * H + tid];
    float a0 = bb, a1 = bb, a2 = bb, a3 = bb;
    const float* w1 = rW1 + (size_t)l * H * H + (size_t)tid * H;
    for (int h = 0; h < H; ++h) {
      float w = w1[h];
      a0 += x[0][h] * w; a1 += x[1][h] * w; a2 += x[2][h] * w; a3 += x[3][h] * w;
    }
    hh[0][tid] = fmaxf(a0, 0.f); hh[1][tid] = fmaxf(a1, 0.f);
    hh[2][tid] = fmaxf(a2, 0.f); hh[3][tid] = fmaxf(a3, 0.f);
    __syncthreads();
    bb = rb2[l * H + tid];
    float b0 = bb, b1 = bb, b2 = bb, b3 = bb;
    const float* w2 = rW2 + (size_t)l * H * H + (size_t)tid * H;
    for (int h = 0; h < H; ++h) {
      float w = w2[h];
      b0 += hh[0][h] * w; b1 += hh[1][h] * w; b2 += hh[2][h] * w; b3 += hh[3][h] * w;
    }
    __syncthreads();
    x[0][tid] += fmaxf(b0, 0.f); x[1][tid] += fmaxf(b1, 0.f);
    x[2][tid] += fmaxf(b2, 0.f); x[3][tid] += fmaxf(b3, 0.f);
    __syncthreads();
  }
  for (int r = 0; r < 4; ++r) ft[(size_t)(r0 + r) * H + tid] = x[r][tid];
}

// ---------- transition: PT[j][i] = softmax_j(se_i . nse_j + band) ----------
__global__ void __launch_bounds__(256) k_trans(
    const float* __restrict__ se, const float* __restrict__ nse,
    const float* __restrict__ band, float* __restrict__ PT) {
  __shared__ float sv[H];
  __shared__ float sl[C];
  __shared__ float rr[256];
  int i = blockIdx.x, tid = threadIdx.x;
  sv[tid] = se[(size_t)i * H + tid];
  __syncthreads();
  #pragma unroll 1
  for (int jq = 0; jq < 4; ++jq) {
    int j = jq * 256 + tid;
    const float4* nr = (const float4*)(nse + (size_t)j * H);
    float acc = 0.f;
    #pragma unroll 8
    for (int h4 = 0; h4 < H / 4; ++h4) {
      float4 nv = nr[h4];
      float4 s4 = *(const float4*)&sv[h4 * 4];
      acc += s4.x * nv.x + s4.y * nv.y + s4.z * nv.z + s4.w * nv.w;
    }
    sl[j] = acc;
  }
  __syncthreads();
  if (tid < K1K) {
    int col = i + tid - K;
    if (col >= 0 && col < C) sl[col] += band[(size_t)i * K1K + tid];
  }
  __syncthreads();
  float m = -__builtin_inff();
  for (int q = 0; q < 4; ++q) m = fmaxf(m, sl[q * 256 + tid]);
  rr[tid] = m; __syncthreads();
  for (int off = 128; off > 0; off >>= 1) { if (tid < off) rr[tid] = fmaxf(rr[tid], rr[tid + off]); __syncthreads(); }
  m = rr[0]; __syncthreads();
  float e[4]; float s = 0.f;
  for (int q = 0; q < 4; ++q) { e[q] = __expf(sl[q * 256 + tid] - m); s += e[q]; }
  rr[tid] = s; __syncthreads();
  for (int off = 128; off > 0; off >>= 1) { if (tid < off) rr[tid] += rr[tid + off]; __syncthreads(); }
  float inv = 1.f / rr[0];
  for (int q = 0; q < 4; ++q) {
    int j = q * 256 + tid;
    PT[(size_t)j * C + i] = e[q] * inv;  // transposed store (scatter once; coalesced preload later)
  }
}

// ---------- emission denominators ----------
__global__ void __launch_bounds__(256) k_denom_part(
    const float* __restrict__ ft, const float* __restrict__ term, float* __restrict__ dpart) {
  constexpr int TJ = 16, VC = V / 8;
  __shared__ float shm[TJ * 4], shs[TJ * 4];
  int tid = threadIdx.x, lane = tid & 63, w = tid >> 6;
  int jg = blockIdx.x >> 3, vc = blockIdx.x & 7;
  const float4* fb = (const float4*)(ft + (size_t)jg * TJ * H);
  float rm[TJ], rs[TJ];
  #pragma unroll
  for (int r = 0; r < TJ; ++r) { rm[r] = -__builtin_inff(); rs[r] = 0.f; }
  int v0 = vc * VC;
  for (int v = v0 + tid; v < v0 + VC; v += 256) {
    const float4* tr = (const float4*)(term + (size_t)v * H);
    float acc[TJ];
    #pragma unroll
    for (int r = 0; r < TJ; ++r) acc[r] = 0.f;
    for (int h4 = 0; h4 < H / 4; ++h4) {
      float4 tv = tr[h4];
      #pragma unroll
      for (int r = 0; r < TJ; ++r) {
        float4 f = fb[r * (H / 4) + h4];
        acc[r] += tv.x * f.x + tv.y * f.y + tv.z * f.z + tv.w * f.w;
      }
    }
    #pragma unroll
    for (int r = 0; r < TJ; ++r) {
      float m2 = fmaxf(rm[r], acc[r]);
      rs[r] = rs[r] * __expf(rm[r] - m2) + __expf(acc[r] - m2);
      rm[r] = m2;
    }
  }
  #pragma unroll
  for (int r = 0; r < TJ; ++r) {
    float m = rm[r], s = rs[r];
    #pragma unroll
    for (int off = 32; off > 0; off >>= 1) {
      float mo = __shfl_xor(m, off), so = __shfl_xor(s, off);
      float m2 = fmaxf(m, mo);
      s = s * __expf(m - m2) + so * __expf(mo - m2);
      m = m2;
    }
    if (lane == 0) { shm[r * 4 + w] = m; shs[r * 4 + w] = s; }
  }
  __syncthreads();
  if (tid < TJ) {
    float m = -__builtin_inff(), s = 0.f;
    for (int w2 = 0; w2 < 4; ++w2) {
      float mo = shm[tid * 4 + w2], so = shs[tid * 4 + w2];
      float m2 = fmaxf(m, mo);
      s = s * __expf(m - m2) + so * __expf(mo - m2);
      m = m2;
    }
    int j = jg * TJ + tid;
    dpart[(j * 8 + vc) * 2 + 0] = m;
    dpart[(j * 8 + vc) * 2 + 1] = s;
  }
}

__global__ void k_denom_comb(const float* __restrict__ dpart, float* __restrict__ denom) {
  int j = blockIdx.x * 256 + threadIdx.x;
  float m = -__builtin_inff(), s = 0.f;
  for (int vc = 0; vc < 8; ++vc) {
    float mo = dpart[(j * 8 + vc) * 2], so = dpart[(j * 8 + vc) * 2 + 1];
    float m2 = fmaxf(m, mo);
    s = s * __expf(m - m2) + so * __expf(mo - m2);
    m = m2;
  }
  denom[j] = m + __logf(s);
}

// ---------- eem[(t*B+b)*C + j] = exp(ft[j].term[tok] - denom[j] + LV) ----------
__global__ void __launch_bounds__(256) k_eemit(
    const int* __restrict__ text, const float* __restrict__ ft,
    const float* __restrict__ denom, const float* __restrict__ term,
    float* __restrict__ eem) {
  int tid = threadIdx.x;
  int n0 = blockIdx.x * 8;
  const float4* trow[8];
  #pragma unroll
  for (int r = 0; r < 8; ++r) {
    int n = n0 + r;
    int tok = text[(n & 7) * T + (n >> 3)];  // text[b*T + t], n = t*B+b
    trow[r] = (const float4*)(term + (size_t)tok * H);
  }
  for (int q = 0; q < 4; ++q) {
    int j = q * 256 + tid;
    const float4* fr = (const float4*)(ft + (size_t)j * H);
    float acc[8];
    #pragma unroll
    for (int r = 0; r < 8; ++r) acc[r] = 0.f;
    for (int h4 = 0; h4 < H / 4; ++h4) {
      float4 f = fr[h4];
      #pragma unroll
      for (int r = 0; r < 8; ++r) {
        float4 tv = trow[r][h4];
        acc[r] += f.x * tv.x + f.y * tv.y + f.z * tv.z + f.w * tv.w;
      }
    }
    float dj = denom[j];
    #pragma unroll
    for (int r = 0; r < 8; ++r) eem[(size_t)(n0 + r) * C + j] = __expf(acc[r] - dj + LV);
  }
}

// ---------- persistent linear-space scan ----------
// 128 blocks = 64 j-groups(16 j) x 2 batch-halves(4 b). Thread (jj=tid>>4, q=tid&15):
// owns PT row slice [myj][i0..i0+64) preloaded in 64 VGPRs (coalesced f4 loads).
__global__ void __launch_bounds__(256, 1) k_scan(
    const float* __restrict__ PT, const float* __restrict__ eem,
    const float* __restrict__ startv, float* __restrict__ ua, float* __restrict__ ub,
    float* __restrict__ umax, unsigned* __restrict__ flags, unsigned* __restrict__ gen,
    float* __restrict__ out) {
  __shared__ __align__(16) float us[4 * 1088];   // swizzled: phys = bb*1088 + i + 4*(i>>6)
  __shared__ __align__(16) float part[16 * 68];  // padded stride 68 -> 2-way max conflicts
  __shared__ float wval[64];
  __shared__ float fred[256];
  const int tid = threadIdx.x, bid = blockIdx.x;
  const int gb = bid & 1, gj = bid >> 1;
  const int b0 = gb * 4, jbase = gj * 16;
  const int jj = tid >> 4, q = tid & 15;
  const int myj = jbase + jj;
  const int i0 = q * 64;

  // preload PT slice (contiguous 256B per thread; 16KB/wave coalesced)
  f4 pv[16];
  {
    const f4* prow = (const f4*)(PT + (size_t)myj * C + i0);
    #pragma unroll
    for (int k4 = 0; k4 < 16; ++k4) pv[k4] = prow[k4];
  }

  const int wjj = tid >> 2, wbb = tid & 3;  // writer role (tid<64)
  float Sacc = 0.f;

  // u_0 = exp(startv) * eem_0
  if (tid < 64) {
    int j = jbase + wjj, b = b0 + wbb;
    gstore(&ua[(size_t)b * C + j], __expf(startv[j]) * eem[(size_t)b * C + j]);
  }
  unsigned ep = 1;
  gsync(flags, gen, bid, ep); ++ep;

  float* ucur = ua;
  float* unxt = ub;

  float em = 0.f;
  if (tid < 64) em = eem[((size_t)1 * B + b0 + wbb) * C + jbase + wjj];

  for (int t = 1; t < T; ++t) {
    // rescale factor (applied one step after sample-max write)
    float imt = 1.f;
    if (tid < 64 && (t & 7) == 1 && t > 1) {
      float m = gload(&umax[((t - 1) >> 3) * 8 + b0 + wbb]);
      imt = 1.f / m;
      Sacc += __logf(m);
    }

    // stage u_prev (4 batches x 1024) into swizzled LDS via coherent 16B loads
    {
      const int f0 = tid * 16;
      const int sbb = f0 >> 10, si = f0 & 1023;
      const float* src = ucur + (size_t)(b0 + sbb) * C + si;
      f4 r0, r1, r2, r3;
      asm volatile(
          "global_load_dwordx4 %0, %4, off sc0 sc1\n\t"
          "global_load_dwordx4 %1, %4, off offset:16 sc0 sc1\n\t"
          "global_load_dwordx4 %2, %4, off offset:32 sc0 sc1\n\t"
          "global_load_dwordx4 %3, %4, off offset:48 sc0 sc1\n\t"
          "s_waitcnt vmcnt(0)"
          : "=&v"(r0), "=&v"(r1), "=&v"(r2), "=&v"(r3)
          : "v"(src)
          : "memory");
      int ph = sbb * 1088 + si + ((si >> 6) << 2);
      *(f4*)&us[ph] = r0;
      *(f4*)&us[ph + 4] = r1;
      *(f4*)&us[ph + 8] = r2;
      *(f4*)&us[ph + 12] = r3;
    }
    __syncthreads();

    // acc[bb] = sum_i u[bb][i] * P[i][myj] over i in [i0, i0+64)
    float a0 = 0.f, a1 = 0.f, a2 = 0.f, a3 = 0.f;
    const int ubo = q * 68;
    #pragma unroll
    for (int k4 = 0; k4 < 16; ++k4) {
      f4 p = pv[k4];
      f4 x0 = *(const f4*)&us[0 * 1088 + ubo + k4 * 4];
      f4 x1 = *(const f4*)&us[1 * 1088 + ubo + k4 * 4];
      f4 x2 = *(const f4*)&us[2 * 1088 + ubo + k4 * 4];
      f4 x3 = *(const f4*)&us[3 * 1088 + ubo + k4 * 4];
      a0 += p.x * x0.x + p.y * x0.y + p.z * x0.z + p.w * x0.w;
      a1 += p.x * x1.x + p.y * x1.y + p.z * x1.z + p.w * x1.w;
      a2 += p.x * x2.x + p.y * x2.y + p.z * x2.z + p.w * x2.w;
      a3 += p.x * x3.x + p.y * x3.y + p.z * x3.z + p.w * x3.w;
    }
    {
      f4 t4; t4.x = a0; t4.y = a1; t4.z = a2; t4.w = a3;
      *(f4*)&part[q * 68 + jj * 4] = t4;
    }
    __syncthreads();

    if (tid < 64) {
      float s = 0.f;
      #pragma unroll
      for (int q2 = 0; q2 < 16; ++q2) s += part[q2 * 68 + tid];
      float val = s * imt * em;
      gstore(&unxt[(size_t)(b0 + wbb) * C + jbase + wjj], val);
      if (gj == 0) wval[tid] = val;
    }
    if (gj == 0 && (t & 7) == 0) {  // sample-max over 16 j's (any common per-batch scale is exact)
      __syncthreads();
      if (tid < 4) {
        float m = wval[tid];
        #pragma unroll
        for (int j2 = 1; j2 < 16; ++j2) m = fmaxf(m, wval[j2 * 4 + tid]);
        gstore(&umax[(t >> 3) * 8 + b0 + tid], m);
      }
    }

    // ---- hierarchical barrier with eem prefetch overlapped into the wait ----
    __syncthreads();
    if (tid == 0) {
      asm volatile("s_waitcnt vmcnt(0)" ::: "memory");
      __hip_atomic_store(&flags[bid * 16], ep, __ATOMIC_RELAXED, __HIP_MEMORY_SCOPE_AGENT);
    }
    float em_next = em;
    if (tid < 64 && t + 1 < T)
      em_next = eem[((size_t)(t + 1) * B + b0 + wbb) * C + jbase + wjj];
    if (bid == 0) {
      if (tid < GS)
        while (__hip_atomic_load(&flags[tid * 16], __ATOMIC_RELAXED,
                                 __HIP_MEMORY_SCOPE_AGENT) < ep) {}
      __syncthreads();
      if (tid == 0)
        __hip_atomic_store(gen, ep, __ATOMIC_RELAXED, __HIP_MEMORY_SCOPE_AGENT);
    } else if (tid == 0) {
      while (__hip_atomic_load(gen, __ATOMIC_RELAXED, __HIP_MEMORY_SCOPE_AGENT) < ep) {}
    }
    __syncthreads();
    ++ep;
    em = em_next;
    float* tp = ucur; ucur = unxt; unxt = tp;
  }

  // final: blocks 0,1 -> out[b] = -T*LV + Sacc_b + log(sum_j u_T[b,j])
  if (gj == 0) {
    #pragma unroll 1
    for (int bb = 0; bb < 4; ++bb) {
      int b = b0 + bb;
      const float* uf = ucur + (size_t)b * C;
      float s = gload(&uf[tid]) + gload(&uf[tid + 256]) + gload(&uf[tid + 512]) + gload(&uf[tid + 768]);
      fred[tid] = s;
      __syncthreads();
      for (int off = 128; off > 0; off >>= 1) {
        if (tid < off) fred[tid] += fred[tid + off];
        __syncthreads();
      }
      if (tid == bb) out[b] = -(float)T * LV + Sacc + __logf(fred[0]);
      __syncthreads();
    }
  }
}

extern "C" void kernel_launch(void* const* d_in, const int* in_sizes, int n_in,
                              void* d_out, int out_size, void* d_ws, size_t ws_size,
                              hipStream_t stream) {
  const int*   text  = (const int*)  d_in[0];
  const float* semb  = (const float*)d_in[1];
  const float* slinW = (const float*)d_in[2];
  const float* slinb = (const float*)d_in[3];
  const float* srW1  = (const float*)d_in[4];
  const float* srb1  = (const float*)d_in[5];
  const float* srW2  = (const float*)d_in[6];
  const float* srb2  = (const float*)d_in[7];
  const float* stemb = (const float*)d_in[8];
  const float* nse   = (const float*)d_in[9];
  const float* pre   = (const float*)d_in[10];
  const float* trW1  = (const float*)d_in[11];
  const float* trb1  = (const float*)d_in[12];
  const float* trW2  = (const float*)d_in[13];
  const float* trb2  = (const float*)d_in[14];
  const float* term  = (const float*)d_in[15];
  const float* band  = (const float*)d_in[16];

  float* ws     = (float*)d_ws;
  float* PT     = ws;                          // C*C (transposed P)
  float* eem    = PT + (size_t)C * C;          // T*B*C
  float* ua     = eem + (size_t)T * B * C;     // B*C
  float* ubuf   = ua + B * C;                  // B*C
  float* ftb    = ubuf + B * C;                // C*H
  float* startv = ftb + (size_t)C * H;         // C
  float* denom  = startv + C;                  // C
  float* dpart  = denom + C;                   // C*16
  float* umax   = dpart + C * 16;              // 32*8
  unsigned* flags = (unsigned*)(umax + 32 * 8);  // GS*16 + gen
  unsigned* gen   = flags + GS * 16 + 16;

  k_init<<<1, 256, 0, stream>>>(flags);
  k_start<<<1, 256, 0, stream>>>(semb, slinW, slinb, srW1, srb1, srW2, srb2, nse, startv);
  k_term_mlp<<<C / 4, 256, 0, stream>>>(pre, trW1, trb1, trW2, trb2, ftb);
  k_trans<<<C, 256, 0, stream>>>(stemb, nse, band, PT);
  k_denom_part<<<(C / 16) * 8, 256, 0, stream>>>(ftb, term, dpart);
  k_denom_comb<<<C / 256, 256, 0, stream>>>(dpart, denom);
  k_eemit<<<(T * B) / 8, 256, 0, stream>>>(text, ftb, denom, term, eem);
  k_scan<<<GS, 256, 0, stream>>>(PT, eem, startv, ua, ubuf, umax, flags, gen, (float*)d_out);
}

// Round 5
// 969.418 us; speedup vs baseline: 6.7927x; 1.5461x over previous
//
#include <hip/hip_runtime.h>

constexpr int C = 1024, H = 256, V = 10000, K = 32, B = 8, T = 256, K1K = 65;
constexpr int DB = 32;            // blocks per batch domain
constexpr int GSCAN = B * DB;     // 256
constexpr float LV = 9.210340371976184f;  // ln(10000)

#define DEV static __device__ __forceinline__

typedef float f4 __attribute__((ext_vector_type(4)));

DEV void gstore(float* p, float v) {
  __hip_atomic_store((unsigned*)p, __float_as_uint(v), __ATOMIC_RELAXED, __HIP_MEMORY_SCOPE_AGENT);
}
DEV float gload(const float* p) {
  return __uint_as_float(__hip_atomic_load((unsigned*)p, __ATOMIC_RELAXED, __HIP_MEMORY_SCOPE_AGENT));
}
DEV void fstore(unsigned* p, unsigned v) {
  __hip_atomic_store(p, v, __ATOMIC_RELAXED, __HIP_MEMORY_SCOPE_AGENT);
}
DEV unsigned fload(const unsigned* p) {
  return __hip_atomic_load(p, __ATOMIC_RELAXED, __HIP_MEMORY_SCOPE_AGENT);
}

// ---------- fused pre-kernel: [0]=flag init, [1]=start, [2..257]=term MLP, [258..1281]=trans ----------
__global__ void __launch_bounds__(256) k_pre(
    const float* __restrict__ semb, const float* __restrict__ linW, const float* __restrict__ linb,
    const float* __restrict__ srW1, const float* __restrict__ srb1,
    const float* __restrict__ srW2, const float* __restrict__ srb2,
    const float* __restrict__ nse, const float* __restrict__ se,
    const float* __restrict__ pre, const float* __restrict__ trW1, const float* __restrict__ trb1,
    const float* __restrict__ trW2, const float* __restrict__ trb2,
    const float* __restrict__ band,
    unsigned* __restrict__ flags, float* __restrict__ startv,
    float* __restrict__ ft, float* __restrict__ PT) {
  __shared__ float smem[2048];
  const int bid = blockIdx.x, tid = threadIdx.x;

  if (bid == 0) {  // zero barrier flags
    for (int k = tid; k < B * DB * 16; k += 256) flags[k] = 0u;
    return;
  }

  if (bid == 1) {  // start vector: MLP + log_softmax over C
    float* sa = smem;        // 256
    float* fx = smem + 256;  // 256
    float* hh = smem + 512;  // 256
    float* sl = smem + 768;  // 1024
    float* red = smem + 1792;
    sa[tid] = semb[tid];
    __syncthreads();
    float acc = linb[tid];
    for (int h = 0; h < H; ++h) acc += sa[h] * linW[tid * H + h];
    fx[tid] = acc;
    __syncthreads();
    for (int l = 0; l < 2; ++l) {
      float a1 = srb1[l * H + tid];
      const float* w1 = srW1 + (size_t)l * H * H + (size_t)tid * H;
      for (int h = 0; h < H; ++h) a1 += fx[h] * w1[h];
      hh[tid] = fmaxf(a1, 0.f);
      __syncthreads();
      float a2 = srb2[l * H + tid];
      const float* w2 = srW2 + (size_t)l * H * H + (size_t)tid * H;
      for (int h = 0; h < H; ++h) a2 += hh[h] * w2[h];
      __syncthreads();
      fx[tid] += fmaxf(a2, 0.f);
      __syncthreads();
    }
    for (int q = 0; q < 4; ++q) {
      int c = q * 256 + tid;
      const float* nr = nse + (size_t)c * H;
      float s = 0.f;
      for (int h = 0; h < H; ++h) s += fx[h] * nr[h];
      sl[c] = s;
    }
    __syncthreads();
    float m = -__builtin_inff();
    for (int q = 0; q < 4; ++q) m = fmaxf(m, sl[q * 256 + tid]);
    red[tid] = m; __syncthreads();
    for (int off = 128; off > 0; off >>= 1) { if (tid < off) red[tid] = fmaxf(red[tid], red[tid + off]); __syncthreads(); }
    m = red[0]; __syncthreads();
    float s = 0.f;
    for (int q = 0; q < 4; ++q) s += __expf(sl[q * 256 + tid] - m);
    red[tid] = s; __syncthreads();
    for (int off = 128; off > 0; off >>= 1) { if (tid < off) red[tid] += red[tid + off]; __syncthreads(); }
    float lse = m + __logf(red[0]);
    for (int q = 0; q < 4; ++q) { int c = q * 256 + tid; startv[c] = sl[c] - lse; }
    return;
  }

  if (bid < 258) {  // terminal MLP, 4 rows/block
    float (*x)[H] = (float(*)[H])smem;
    float (*hh)[H] = (float(*)[H])(smem + 1024);
    int r0 = (bid - 2) * 4;
    for (int r = 0; r < 4; ++r) x[r][tid] = pre[(size_t)(r0 + r) * H + tid];
    __syncthreads();
    for (int l = 0; l < 2; ++l) {
      float bb = trb1[l * H + tid];
      float a0 = bb, a1 = bb, a2 = bb, a3 = bb;
      const float* w1 = trW1 + (size_t)l * H * H + (size_t)tid * H;
      for (int h = 0; h < H; ++h) {
        float w = w1[h];
        a0 += x[0][h] * w; a1 += x[1][h] * w; a2 += x[2][h] * w; a3 += x[3][h] * w;
      }
      hh[0][tid] = fmaxf(a0, 0.f); hh[1][tid] = fmaxf(a1, 0.f);
      hh[2][tid] = fmaxf(a2, 0.f); hh[3][tid] = fmaxf(a3, 0.f);
      __syncthreads();
      bb = trb2[l * H + tid];
      float b0 = bb, b1 = bb, b2 = bb, b3 = bb;
      const float* w2 = trW2 + (size_t)l * H * H + (size_t)tid * H;
      for (int h = 0; h < H; ++h) {
        float w = w2[h];
        b0 += hh[0][h] * w; b1 += hh[1][h] * w; b2 += hh[2][h] * w; b3 += hh[3][h] * w;
      }
      __syncthreads();
      x[0][tid] += fmaxf(b0, 0.f); x[1][tid] += fmaxf(b1, 0.f);
      x[2][tid] += fmaxf(b2, 0.f); x[3][tid] += fmaxf(b3, 0.f);
      __syncthreads();
    }
    for (int r = 0; r < 4; ++r) ft[(size_t)(r0 + r) * H + tid] = x[r][tid];
    return;
  }

  // transition row i: PT[j][i] = softmax_j(se_i . nse_j + band)
  {
    float* sv = smem;         // 256
    float* sl = smem + 256;   // 1024
    float* rr = smem + 1280;  // 256
    int i = bid - 258;
    sv[tid] = se[(size_t)i * H + tid];
    __syncthreads();
    #pragma unroll 1
    for (int jq = 0; jq < 4; ++jq) {
      int j = jq * 256 + tid;
      const float4* nr = (const float4*)(nse + (size_t)j * H);
      float acc = 0.f;
      #pragma unroll 8
      for (int h4 = 0; h4 < H / 4; ++h4) {
        float4 nv = nr[h4];
        float4 s4 = *(const float4*)&sv[h4 * 4];
        acc += s4.x * nv.x + s4.y * nv.y + s4.z * nv.z + s4.w * nv.w;
      }
      sl[j] = acc;
    }
    __syncthreads();
    if (tid < K1K) {
      int col = i + tid - K;
      if (col >= 0 && col < C) sl[col] += band[(size_t)i * K1K + tid];
    }
    __syncthreads();
    float m = -__builtin_inff();
    for (int q = 0; q < 4; ++q) m = fmaxf(m, sl[q * 256 + tid]);
    rr[tid] = m; __syncthreads();
    for (int off = 128; off > 0; off >>= 1) { if (tid < off) rr[tid] = fmaxf(rr[tid], rr[tid + off]); __syncthreads(); }
    m = rr[0]; __syncthreads();
    float e[4]; float s = 0.f;
    for (int q = 0; q < 4; ++q) { e[q] = __expf(sl[q * 256 + tid] - m); s += e[q]; }
    rr[tid] = s; __syncthreads();
    for (int off = 128; off > 0; off >>= 1) { if (tid < off) rr[tid] += rr[tid + off]; __syncthreads(); }
    float inv = 1.f / rr[0];
    for (int q = 0; q < 4; ++q) {
      int j = q * 256 + tid;
      PT[(size_t)j * C + i] = e[q] * inv;  // transposed store; coalesced preload in k_scan
    }
  }
}

// ---------- emission denominators ----------
__global__ void __launch_bounds__(256) k_denom_part(
    const float* __restrict__ ft, const float* __restrict__ term, float* __restrict__ dpart) {
  constexpr int TJ = 16, VC = V / 8;
  __shared__ float shm[TJ * 4], shs[TJ * 4];
  int tid = threadIdx.x, lane = tid & 63, w = tid >> 6;
  int jg = blockIdx.x >> 3, vc = blockIdx.x & 7;
  const float4* fb = (const float4*)(ft + (size_t)jg * TJ * H);
  float rm[TJ], rs[TJ];
  #pragma unroll
  for (int r = 0; r < TJ; ++r) { rm[r] = -__builtin_inff(); rs[r] = 0.f; }
  int v0 = vc * VC;
  for (int v = v0 + tid; v < v0 + VC; v += 256) {
    const float4* tr = (const float4*)(term + (size_t)v * H);
    float acc[TJ];
    #pragma unroll
    for (int r = 0; r < TJ; ++r) acc[r] = 0.f;
    for (int h4 = 0; h4 < H / 4; ++h4) {
      float4 tv = tr[h4];
      #pragma unroll
      for (int r = 0; r < TJ; ++r) {
        float4 f = fb[r * (H / 4) + h4];
        acc[r] += tv.x * f.x + tv.y * f.y + tv.z * f.z + tv.w * f.w;
      }
    }
    #pragma unroll
    for (int r = 0; r < TJ; ++r) {
      float m2 = fmaxf(rm[r], acc[r]);
      rs[r] = rs[r] * __expf(rm[r] - m2) + __expf(acc[r] - m2);
      rm[r] = m2;
    }
  }
  #pragma unroll
  for (int r = 0; r < TJ; ++r) {
    float m = rm[r], s = rs[r];
    #pragma unroll
    for (int off = 32; off > 0; off >>= 1) {
      float mo = __shfl_xor(m, off), so = __shfl_xor(s, off);
      float m2 = fmaxf(m, mo);
      s = s * __expf(m - m2) + so * __expf(mo - m2);
      m = m2;
    }
    if (lane == 0) { shm[r * 4 + w] = m; shs[r * 4 + w] = s; }
  }
  __syncthreads();
  if (tid < TJ) {
    float m = -__builtin_inff(), s = 0.f;
    for (int w2 = 0; w2 < 4; ++w2) {
      float mo = shm[tid * 4 + w2], so = shs[tid * 4 + w2];
      float m2 = fmaxf(m, mo);
      s = s * __expf(m - m2) + so * __expf(mo - m2);
      m = m2;
    }
    int j = jg * TJ + tid;
    dpart[(j * 8 + vc) * 2 + 0] = m;
    dpart[(j * 8 + vc) * 2 + 1] = s;
  }
}

__global__ void k_denom_comb(const float* __restrict__ dpart, float* __restrict__ denom) {
  int j = blockIdx.x * 256 + threadIdx.x;
  float m = -__builtin_inff(), s = 0.f;
  for (int vc = 0; vc < 8; ++vc) {
    float mo = dpart[(j * 8 + vc) * 2], so = dpart[(j * 8 + vc) * 2 + 1];
    float m2 = fmaxf(m, mo);
    s = s * __expf(m - m2) + so * __expf(mo - m2);
    m = m2;
  }
  denom[j] = m + __logf(s);
}

// ---------- eem[(t*B+b)*C + j] = exp(ft[j].term[tok] - denom[j] + LV) ----------
__global__ void __launch_bounds__(256) k_eemit(
    const int* __restrict__ text, const float* __restrict__ ft,
    const float* __restrict__ denom, const float* __restrict__ term,
    float* __restrict__ eem) {
  int tid = threadIdx.x;
  int n0 = blockIdx.x * 8;
  const float4* trow[8];
  #pragma unroll
  for (int r = 0; r < 8; ++r) {
    int n = n0 + r;
    int tok = text[(n & 7) * T + (n >> 3)];  // text[b*T + t], n = t*B+b
    trow[r] = (const float4*)(term + (size_t)tok * H);
  }
  for (int q = 0; q < 4; ++q) {
    int j = q * 256 + tid;
    const float4* fr = (const float4*)(ft + (size_t)j * H);
    float acc[8];
    #pragma unroll
    for (int r = 0; r < 8; ++r) acc[r] = 0.f;
    for (int h4 = 0; h4 < H / 4; ++h4) {
      float4 f = fr[h4];
      #pragma unroll
      for (int r = 0; r < 8; ++r) {
        float4 tv = trow[r][h4];
        acc[r] += f.x * tv.x + f.y * tv.y + f.z * tv.z + f.w * tv.w;
      }
    }
    float dj = denom[j];
    #pragma unroll
    for (int r = 0; r < 8; ++r) eem[(size_t)(n0 + r) * C + j] = __expf(acc[r] - dj + LV);
  }
}

// ---------- persistent linear-space scan, per-batch flat 2-hop barrier ----------
// 256 blocks = 8 batches (bid&7 -> same XCD under round-robin) x 32 blocks.
// Block: batch b, j-range blk*32..+32. Thread: jloc=tid>>3, s=tid&7; owns P[jloc][s*128..+128) in regs.
__global__ void __launch_bounds__(256, 1) k_scan(
    const float* __restrict__ PT, const float* __restrict__ eem,
    const float* __restrict__ startv, float* __restrict__ pay,
    float* __restrict__ umax, unsigned* __restrict__ flags, float* __restrict__ out) {
  __shared__ __align__(16) float us[8 * 132];  // chunk s at s*132 (pad 4) -> conflict-free reads
  __shared__ float wv[32];
  __shared__ float fred[256];
  const int tid = threadIdx.x, bid = blockIdx.x;
  const int b = bid & 7, blk = bid >> 3;
  const int jbase = blk * 32;
  const int jloc = tid >> 3, s = tid & 7;
  const int myj = jbase + jloc;
  const bool owner = (s == 0);

  // preload P slice: pv[k4] = PT[myj][s*128 + 4k4 .. +3]  (contiguous 512B/thread)
  f4 pv[32];
  {
    const f4* prow = (const f4*)(PT + (size_t)myj * C + s * 128);
    #pragma unroll
    for (int k4 = 0; k4 < 32; ++k4) pv[k4] = prow[k4];
  }

  unsigned* myflag = &flags[(b * DB + blk) * 16];
  float Sacc = 0.f;

  // u_0 = exp(startv)*eem_0 -> payload buf 0
  if (owner) {
    float u0 = __expf(startv[myj]) * eem[(size_t)b * C + myj];
    gstore(&pay[(size_t)b * (DB * DB) + blk * DB + jloc], u0);
  }
  __syncthreads();  // drains vmcnt -> payload globally visible before flag
  if (tid == 0) fstore(myflag, 1u);

  float em = 0.f;
  if (owner) em = eem[((size_t)1 * B + b) * C + myj];  // prefetch t=1

  for (int t = 1; t < T; ++t) {
    // wait: all domain blocks published u_{t-1} (flag >= t)
    if (tid < DB) {
      while (fload(&flags[(b * DB + tid) * 16]) < (unsigned)t) {}
    }
    __syncthreads();

    // rescale factor (slot written at t-1 = 0 mod 8, applied here)
    float imt = 1.f;
    if (owner && (t & 7) == 1 && t > 1) {
      float m = gload(&umax[((t - 1) >> 3) * 8 + b]);
      imt = 1.f / m;
      Sacc += __logf(m);
    }

    // stage payload buf (t-1)&1 into LDS (one f4 per thread, 4KB total)
    {
      int i = (tid >> 3) * 32 + (tid & 7) * 4;
      const float* src = pay + (size_t)(((t - 1) & 1) * 8 + b) * (DB * DB) + i;
      f4 r;
      asm volatile("global_load_dwordx4 %0, %1, off sc0 sc1\n\ts_waitcnt vmcnt(0)"
                   : "=v"(r) : "v"(src) : "memory");
      int ph = (i >> 7) * 132 + (i & 127);
      *(f4*)&us[ph] = r;
    }
    __syncthreads();

    // acc = sum over my i-slice; reduce across the 8 s-lanes of this j
    float acc = 0.f;
    {
      const int ubo = s * 132;
      #pragma unroll
      for (int k4 = 0; k4 < 32; ++k4) {
        f4 p = pv[k4];
        f4 x = *(const f4*)&us[ubo + k4 * 4];
        acc += p.x * x.x + p.y * x.y + p.z * x.z + p.w * x.w;
      }
    }
    acc += __shfl_xor(acc, 1);
    acc += __shfl_xor(acc, 2);
    acc += __shfl_xor(acc, 4);

    if (owner) {
      float val = acc * imt * em;
      gstore(&pay[(size_t)((t & 1) * 8 + b) * (DB * DB) + blk * DB + jloc], val);
      if (blk == 0) wv[jloc] = val;
    }
    __syncthreads();  // drains payload stores (and orders wv)

    if (blk == 0 && (t & 7) == 0 && tid == 0) {  // sample-max (any common scale is exact)
      float m = wv[0];
      #pragma unroll
      for (int j2 = 1; j2 < 32; ++j2) m = fmaxf(m, wv[j2]);
      gstore(&umax[(t >> 3) * 8 + b], m);
      asm volatile("s_waitcnt vmcnt(0)" ::: "memory");  // umax visible before flag
    }
    if (tid == 0) fstore(myflag, (unsigned)(t + 1));
    if (owner && t + 1 < T) em = eem[((size_t)(t + 1) * B + b) * C + myj];  // overlap into wait
  }

  // final: block 0 of each batch reduces u_{T-1}
  if (tid < DB) {
    while (fload(&flags[(b * DB + tid) * 16]) < (unsigned)T) {}
  }
  __syncthreads();
  if (blk == 0) {
    {
      int i = (tid >> 3) * 32 + (tid & 7) * 4;
      const float* src = pay + (size_t)(((T - 1) & 1) * 8 + b) * (DB * DB) + i;
      f4 r;
      asm volatile("global_load_dwordx4 %0, %1, off sc0 sc1\n\ts_waitcnt vmcnt(0)"
                   : "=v"(r) : "v"(src) : "memory");
      int ph = (i >> 7) * 132 + (i & 127);
      *(f4*)&us[ph] = r;
    }
    __syncthreads();
    float ss = 0.f;
    for (int idx = tid; idx < C; idx += 256) ss += us[(idx >> 7) * 132 + (idx & 127)];
    fred[tid] = ss;
    __syncthreads();
    for (int off = 128; off > 0; off >>= 1) {
      if (tid < off) fred[tid] += fred[tid + off];
      __syncthreads();
    }
    if (tid == 0) out[b] = -(float)T * LV + Sacc + __logf(fred[0]);
  }
}

extern "C" void kernel_launch(void* const* d_in, const int* in_sizes, int n_in,
                              void* d_out, int out_size, void* d_ws, size_t ws_size,
                              hipStream_t stream) {
  const int*   text  = (const int*)  d_in[0];
  const float* semb  = (const float*)d_in[1];
  const float* slinW = (const float*)d_in[2];
  const float* slinb = (const float*)d_in[3];
  const float* srW1  = (const float*)d_in[4];
  const float* srb1  = (const float*)d_in[5];
  const float* srW2  = (const float*)d_in[6];
  const float* srb2  = (const float*)d_in[7];
  const float* stemb = (const float*)d_in[8];
  const float* nse   = (const float*)d_in[9];
  const float* pre   = (const float*)d_in[10];
  const float* trW1  = (const float*)d_in[11];
  const float* trb1  = (const float*)d_in[12];
  const float* trW2  = (const float*)d_in[13];
  const float* trb2  = (const float*)d_in[14];
  const float* term  = (const float*)d_in[15];
  const float* band  = (const float*)d_in[16];

  float* ws     = (float*)d_ws;
  float* PT     = ws;                          // C*C (transposed P)
  float* eem    = PT + (size_t)C * C;          // T*B*C
  float* pay    = eem + (size_t)T * B * C;     // 2*8*32*32
  float* ftb    = pay + 2 * 8 * DB * DB;       // C*H
  float* startv = ftb + (size_t)C * H;         // C
  float* denom  = startv + C;                  // C
  float* dpart  = denom + C;                   // C*16
  float* umax   = dpart + C * 16;              // 32*8
  unsigned* flags = (unsigned*)(umax + 32 * 8);  // B*DB*16

  k_pre<<<1282, 256, 0, stream>>>(semb, slinW, slinb, srW1, srb1, srW2, srb2,
                                  nse, stemb, pre, trW1, trb1, trW2, trb2, band,
                                  flags, startv, ftb, PT);
  k_denom_part<<<(C / 16) * 8, 256, 0, stream>>>(ftb, term, dpart);
  k_denom_comb<<<C / 256, 256, 0, stream>>>(dpart, denom);
  k_eemit<<<(T * B) / 8, 256, 0, stream>>>(text, ftb, denom, term, eem);
  k_scan<<<GSCAN, 256, 0, stream>>>(PT, eem, startv, pay, umax, flags, (float*)d_out);
}